// Round 8
// baseline (16005.539 us; speedup 1.0000x reference)
//
#include <hip/hip_runtime.h>

// LSTM: B=256, T=512, I=64, H=512, G=4H=2048.
// gates = W @ [h; x], W = [R | kernel^T], K = 576 (18 K-tiles of 32).
// Persistent: 32 WGs x 1024 thr = 16 groups x 2 WGs (p=0/1 owns 256 h-cols).
// W slice pinned in AGPRs (288/lane). MFMA split: part1 = own+x K-tiles
// (runs while peer's h publish is in flight), part2 = peer K-tiles after a
// tagged-data poll (fan-in 1). Peer LDS region parity double-buffered.
// K-tiles are stored REORDERED per slice: local 0..7 = own half, 8..15 =
// peer half, 16..17 = x  -> W register indices stay compile-time.
#define TSTEPS 512
#define BATCH  256
#define ISZ    64
#define HSZ    512
#define GSZ    2048
#define NKT    18
#define BG     16
#define ROWU   856          // LDS row length (ushorts): 584 + 256 + 16 pad
#define PAR_STRIDE 131072   // u32s per parity plane: 256*512

typedef __attribute__((ext_vector_type(8))) short short8;
typedef __attribute__((ext_vector_type(4))) float f32x4;
typedef __attribute__((ext_vector_type(4))) unsigned int u32x4;

static __device__ __forceinline__ unsigned short f2bf(float f) {
    unsigned int u = __float_as_uint(f);
    return (unsigned short)((u + 0x7fffu + ((u >> 16) & 1u)) >> 16);  // RNE
}
static __device__ __forceinline__ float sig_(float x) {
    return 1.0f / (1.0f + __expf(-x));
}
static __device__ __forceinline__ float tanh_(float x) {
    float e = __expf(-2.0f * fabsf(x));
    float t = (1.0f - e) / (1.0f + e);
    return copysignf(t, x);
}
static __device__ __forceinline__ unsigned ld_tag(const unsigned* p) {
    return __hip_atomic_load(p, __ATOMIC_RELAXED, __HIP_MEMORY_SCOPE_AGENT);
}
static __device__ __forceinline__ void st_tag(unsigned* p, unsigned v) {
    __hip_atomic_store(p, v, __ATOMIC_RELAXED, __HIP_MEMORY_SCOPE_AGENT);
}

// Pack W = [R | kernel^T] into bf16 MFMA A-frag order with PER-SLICE K-tile
// reordering: slice jj (own half = [8,16) if jj>=8 else [0,8)) stores
// local kt 0..7 = own-half global kts, 8..15 = peer-half, 16..17 = x.
__global__ void pack_w(const float* __restrict__ R, const float* __restrict__ Kin,
                       unsigned short* __restrict__ wpack)
{
    const int t   = blockIdx.x * 256 + threadIdx.x;
    const int l   = t & 63;
    const int ktl = (t >> 6) % NKT;          // local kt
    const int m   = (t / (64 * NKT)) & 7;
    const int jj  = t / (64 * NKT * 8);
    const int own = (jj >= 8) ? 8 : 0;
    const int ktg = (ktl < 8) ? (own + ktl)
                  : (ktl < 16) ? ((8 - own) + (ktl - 8)) : ktl;  // global kt
    const int r   = 16 * m + (l & 15);
    const int q   = r & 3;
    const int hco = r >> 2;
    const int grow  = q * HSZ + jj * 32 + hco;
    const int kbase = ktg * 32 + (l >> 4) * 8;
    unsigned int pk[4];
#pragma unroll
    for (int pp = 0; pp < 4; ++pp) {
        const int k0 = kbase + 2 * pp;
        const int k1 = k0 + 1;
        const float f0 = (k0 < HSZ) ? R[(size_t)grow * HSZ + k0]
                                    : Kin[(size_t)(k0 - HSZ) * GSZ + grow];
        const float f1 = (k1 < HSZ) ? R[(size_t)grow * HSZ + k1]
                                    : Kin[(size_t)(k1 - HSZ) * GSZ + grow];
        pk[pp] = (unsigned)f2bf(f0) | ((unsigned)f2bf(f1) << 16);
    }
    uint4 v = make_uint4(pk[0], pk[1], pk[2], pk[3]);
    *reinterpret_cast<uint4*>(wpack + (size_t)t * 8) = v;
}

// Zero tagged h planes each launch (tag 0 matches no s>=1): replay-safe.
__global__ void zero_tags(u32x4* __restrict__ hb) {
    u32x4 z = {0u, 0u, 0u, 0u};
    hb[blockIdx.x * 256 + threadIdx.x] = z;
}

__global__ __launch_bounds__(1024, 1) void lstm_persist(
    const unsigned short* __restrict__ wpack,
    const float* __restrict__ input_seq,
    const float* __restrict__ bias,
    unsigned int* __restrict__ tbuf,     // [2 parity][256 b][512 col] tagged u32
    float* __restrict__ hlast)
{
    __shared__ __align__(16) unsigned short lds_B[16][ROWU];
    const int tid = threadIdx.x;
    const int bid = blockIdx.x;          // 32 WGs
    const int gi  = bid & 15;            // batch-group
    const int p   = bid >> 4;            // half owner; pair (g, g+16) same XCD
    const int q   = 1 - p;

    const int w  = tid >> 6;             // wave 0..15
    const int l  = tid & 63;
    const int bb = l & 15;
    const int lg = l >> 4;
    const int jj = p * 8 + (w >> 1);     // gate-slice (own half)
    const int mbase = (w & 1) * 4;

    // ---- one-time: W slice -> 72 frags, PINNED into AGPRs (288/lane) ----
    short8 wf[4][NKT];
#pragma unroll
    for (int mi = 0; mi < 4; ++mi)
#pragma unroll
        for (int kt = 0; kt < NKT; ++kt)
            wf[mi][kt] = *reinterpret_cast<const short8*>(
                wpack + (((size_t)(jj * 8 + mbase + mi) * NKT + kt) * 64 + l) * 8);
#pragma unroll
    for (int mi = 0; mi < 4; ++mi)
#pragma unroll
        for (int kt = 0; kt < NKT; ++kt)
            asm volatile("" : "+a"(wf[mi][kt]));

    int ghc[4];
    float bs[4][4];
#pragma unroll
    for (int mi = 0; mi < 4; ++mi) {
        ghc[mi] = jj * 32 + 4 * (mbase + mi) + lg;     // own-half col
#pragma unroll
        for (int qg = 0; qg < 4; ++qg) bs[mi][qg] = bias[qg * HSZ + ghc[mi]];
    }
    float cc[4] = {0.f, 0.f, 0.f, 0.f};

    const int ownOff  = p * 256;         // LDS col offset of own-half kts
    // prologue: zero h cols [0,512) (own + par0 peer region); stage x(0)
    {
        const int zb = tid >> 6, zc = (tid & 63) * 8;
        u32x4 z = {0u, 0u, 0u, 0u};
        *reinterpret_cast<u32x4*>(&lds_B[zb][zc]) = z;
    }
    const int sb = tid & 15, sc = tid >> 4;       // x staging (tid<512)
    const float* xbase = input_seq + (size_t)(gi * BG + sb) * (TSTEPS * ISZ) + sc * 2;
    float2 xr = {0.f, 0.f};
    if (tid < 512) {
        xr = *reinterpret_cast<const float2*>(xbase);
        unsigned px = (unsigned)f2bf(xr.x) | ((unsigned)f2bf(xr.y) << 16);
        *reinterpret_cast<unsigned*>(&lds_B[sb][HSZ + sc * 2]) = px;
        xr = *reinterpret_cast<const float2*>(xbase + ISZ);   // x(1)
    }
    // poll/stage mapping: thread -> (batch pb, 4-col chunk ch) of peer half
    const int pb = tid >> 6, ch = tid & 63;
    const unsigned* polBase = tbuf + (size_t)(gi * BG + pb) * HSZ + q * 256 + ch * 4;
    __syncthreads();

    for (int s = 0; s < TSTEPS; ++s) {
        const int par = s & 1;
        f32x4 acc[4];
#pragma unroll
        for (int mi = 0; mi < 4; ++mi) acc[mi] = (f32x4){0.f, 0.f, 0.f, 0.f};

        // ---- part 1: own K-tiles (local 0..7) + x tiles (16,17) ----
#define MF(KT, COL)                                                              \
        {                                                                        \
            const short8 bf = *reinterpret_cast<const short8*>(                  \
                &lds_B[bb][(COL) + lg * 8]);                                     \
            acc[0] = __builtin_amdgcn_mfma_f32_16x16x32_bf16(wf[0][KT], bf, acc[0], 0, 0, 0); \
            acc[1] = __builtin_amdgcn_mfma_f32_16x16x32_bf16(wf[1][KT], bf, acc[1], 0, 0, 0); \
            acc[2] = __builtin_amdgcn_mfma_f32_16x16x32_bf16(wf[2][KT], bf, acc[2], 0, 0, 0); \
            acc[3] = __builtin_amdgcn_mfma_f32_16x16x32_bf16(wf[3][KT], bf, acc[3], 0, 0, 0); \
        }
#pragma unroll
        for (int kt = 0; kt < 8; ++kt) MF(kt, ownOff + kt * 32)
        MF(16, 512) MF(17, 544)

        // ---- poll peer half of h(s): tagged data (fan-in 1) ----
        if (s > 0) {
            const unsigned want = (unsigned)s;
            const unsigned* src = polBase + (size_t)par * PAR_STRIDE;
            unsigned v0, v1, v2, v3;
            do {
                v0 = ld_tag(src); v1 = ld_tag(src + 1);
                v2 = ld_tag(src + 2); v3 = ld_tag(src + 3);
            } while ((v0 >> 16) != want || (v1 >> 16) != want ||
                     (v2 >> 16) != want || (v3 >> 16) != want);
            uint2 pkd;
            pkd.x = (v0 & 0xFFFFu) | (v1 << 16);
            pkd.y = (v2 & 0xFFFFu) | (v3 << 16);
            const int pcol = par ? (584 + ch * 4) : (q * 256 + ch * 4);
            *reinterpret_cast<uint2*>(&lds_B[pb][pcol]) = pkd;
        }
        __syncthreads();   // MID: peer staged; all part-1 reads done

        // stage x(s+1) (x region free after MID); prefetch x(s+2)
        if (tid < 512 && s + 1 < TSTEPS) {
            unsigned px = (unsigned)f2bf(xr.x) | ((unsigned)f2bf(xr.y) << 16);
            *reinterpret_cast<unsigned*>(&lds_B[sb][HSZ + sc * 2]) = px;
            if (s + 2 < TSTEPS)
                xr = *reinterpret_cast<const float2*>(xbase + (size_t)(s + 2) * ISZ);
        }

        // ---- part 2: peer K-tiles (local 8..15) ----
        {
            const int peerOff = par ? 584 : q * 256;
#pragma unroll
            for (int kt = 8; kt < 16; ++kt) MF(kt, peerOff + (kt - 8) * 32)
        }
#undef MF

        // ---- cell update ----
        if (s == TSTEPS - 1) {
#pragma unroll
            for (int mi = 0; mi < 4; ++mi) {
                const float fg = sig_(acc[mi][0] + bs[mi][0]);
                const float ig = sig_(acc[mi][1] + bs[mi][1]);
                const float cp = tanh_(acc[mi][2] + bs[mi][2]);
                const float og = sig_(acc[mi][3] + bs[mi][3]);
                cc[mi] = fg * cc[mi] + ig * cp;
                hlast[(size_t)(gi * BG + bb) * HSZ + ghc[mi]] = og * tanh_(cc[mi]);
            }
            break;
        }
        {
            const unsigned t16 = (unsigned)(s + 1) << 16;
            unsigned* pubBase = tbuf + (size_t)((s + 1) & 1) * PAR_STRIDE +
                                (size_t)(gi * BG + bb) * HSZ;
#pragma unroll
            for (int mi = 0; mi < 4; ++mi) {
                const float fg = sig_(acc[mi][0] + bs[mi][0]);
                const float ig = sig_(acc[mi][1] + bs[mi][1]);
                const float cp = tanh_(acc[mi][2] + bs[mi][2]);
                const float og = sig_(acc[mi][3] + bs[mi][3]);
                cc[mi] = fg * cc[mi] + ig * cp;
                const unsigned short h16 = f2bf(og * tanh_(cc[mi]));
                lds_B[bb][ghc[mi]] = h16;              // own use (next part 1)
                st_tag(pubBase + ghc[mi], t16 | h16);  // peer use
            }
        }
        __syncthreads();   // END: own-h/x writes visible before next part 1
    }
}

// out[b] = h_last[b,:] . Wout + bout
__global__ void out_kernel(const float* __restrict__ hlast,
                           const float* __restrict__ wout,
                           const float* __restrict__ bout,
                           float* __restrict__ out)
{
    const int b = blockIdx.x;
    const int l = threadIdx.x;
    float p = 0.f;
    for (int k = l; k < HSZ; k += 64)
        p += hlast[(size_t)b * HSZ + k] * wout[k];
    for (int off = 32; off > 0; off >>= 1)
        p += __shfl_down(p, off, 64);
    if (l == 0) out[b] = p + bout[0];
}

extern "C" void kernel_launch(void* const* d_in, const int* in_sizes, int n_in,
                              void* d_out, int out_size, void* d_ws, size_t ws_size,
                              hipStream_t stream) {
    const float* input_seq = (const float*)d_in[0];
    const float* Kin       = (const float*)d_in[1];
    const float* R         = (const float*)d_in[2];
    const float* bias      = (const float*)d_in[3];
    const float* Wout      = (const float*)d_in[4];
    const float* bout      = (const float*)d_in[5];
    float* out = (float*)d_out;

    char* ws = (char*)d_ws;
    unsigned short* wpack = (unsigned short*)(ws);                    // 2,359,296 B
    unsigned int* tbuf    = (unsigned int*)(ws + 2359296);            // 2,097,152 B
    float* hlast          = (float*)(ws + 2359296 + 2097152);         //   524,288 B

    zero_tags<<<dim3(512), dim3(256), 0, stream>>>((u32x4*)tbuf);
    pack_w<<<dim3(576), dim3(256), 0, stream>>>(R, Kin, wpack);
    lstm_persist<<<dim3(32), dim3(1024), 0, stream>>>(
        wpack, input_seq, bias, tbuf, hlast);
    out_kernel<<<dim3(256), dim3(64), 0, stream>>>(hlast, Wout, bout, out);
}

// Round 9
// 6546.481 us; speedup vs baseline: 2.4449x; 2.4449x over previous
//
#include <hip/hip_runtime.h>

// LSTM: B=256, T=512, I=64, H=512, G=4H=2048.
// gates = W @ [h; x], W = [R | kernel^T], K = 576 (18 K-tiles of 32).
// Persistent: 64 WGs x 1024 thr = 16 groups x 4 WGs; WG owns 128 h-cols
// (512 gate-rows). W slice in AGPRs: 144/lane (wA[18]+wB[18]) -- the
// round-7-proven count; 288 was illegal (AGPR file caps at 256).
// Part1 MFMA = own 4 kts + x 2 kts (no peer dep; hides publish RTT);
// poll = tagged u64 data (fan-in 3 peers); part2 = 12 peer kts.
// K-tiles reordered per slice in pack_w so W reg indices are compile-time.
#define TSTEPS 512
#define BATCH  256
#define ISZ    64
#define HSZ    512
#define GSZ    2048
#define NKT    18
#define BG     16
#define ROWU   584          // LDS row: 512 h + 64 x + 8 pad (u16)
#define PAR_STRIDE 131072   // u32 per parity plane: 256*512

typedef __attribute__((ext_vector_type(8))) short short8;
typedef __attribute__((ext_vector_type(4))) float f32x4;
typedef __attribute__((ext_vector_type(4))) unsigned int u32x4;
typedef unsigned long long u64t;

static __device__ __forceinline__ unsigned short f2bf(float f) {
    unsigned int u = __float_as_uint(f);
    return (unsigned short)((u + 0x7fffu + ((u >> 16) & 1u)) >> 16);  // RNE
}
static __device__ __forceinline__ float sig_(float x) {
    return 1.0f / (1.0f + __expf(-x));
}
static __device__ __forceinline__ float tanh_(float x) {
    float e = __expf(-2.0f * fabsf(x));
    float t = (1.0f - e) / (1.0f + e);
    return copysignf(t, x);
}
static __device__ __forceinline__ u64t ld_tag64(const u64t* p) {
    return __hip_atomic_load(p, __ATOMIC_RELAXED, __HIP_MEMORY_SCOPE_AGENT);
}
static __device__ __forceinline__ void st_tag32(unsigned* p, unsigned v) {
    __hip_atomic_store(p, v, __ATOMIC_RELAXED, __HIP_MEMORY_SCOPE_AGENT);
}

// Pack W = [R | kernel^T] into bf16 MFMA A-frag order, K-tiles reordered per
// slice jj (own block O = jj>>2): local kt 0..3 = global O*4+kt (own),
// 4..15 = the other 12 h kts in ascending global order, 16..17 = x kts.
__global__ void pack_w(const float* __restrict__ R, const float* __restrict__ Kin,
                       unsigned short* __restrict__ wpack)
{
    const int t   = blockIdx.x * 256 + threadIdx.x;
    const int l   = t & 63;
    const int ktl = (t >> 6) % NKT;
    const int m   = (t / (64 * NKT)) & 7;
    const int jj  = t / (64 * NKT * 8);
    const int O4  = (jj >> 2) * 4;
    int ktg;
    if (ktl < 4)       ktg = O4 + ktl;
    else if (ktl < 16) { const int idx = ktl - 4; ktg = (idx < O4) ? idx : idx + 4; }
    else               ktg = ktl;   // 16,17 = x
    const int r   = 16 * m + (l & 15);
    const int q   = r & 3;
    const int hco = r >> 2;
    const int grow  = q * HSZ + jj * 32 + hco;
    const int kbase = ktg * 32 + (l >> 4) * 8;
    unsigned int pk[4];
#pragma unroll
    for (int pp = 0; pp < 4; ++pp) {
        const int k0 = kbase + 2 * pp;
        const int k1 = k0 + 1;
        const float f0 = (k0 < HSZ) ? R[(size_t)grow * HSZ + k0]
                                    : Kin[(size_t)(k0 - HSZ) * GSZ + grow];
        const float f1 = (k1 < HSZ) ? R[(size_t)grow * HSZ + k1]
                                    : Kin[(size_t)(k1 - HSZ) * GSZ + grow];
        pk[pp] = (unsigned)f2bf(f0) | ((unsigned)f2bf(f1) << 16);
    }
    uint4 v = make_uint4(pk[0], pk[1], pk[2], pk[3]);
    *reinterpret_cast<uint4*>(wpack + (size_t)t * 8) = v;
}

// Zero tagged planes each launch (tag 0 matches no s>=1): replay-safe.
__global__ void zero_tags(u32x4* __restrict__ hb) {
    u32x4 z = {0u, 0u, 0u, 0u};
    hb[blockIdx.x * 256 + threadIdx.x] = z;
}

__global__ __launch_bounds__(1024, 4) void lstm_persist(
    const unsigned short* __restrict__ wpack,
    const float* __restrict__ input_seq,
    const float* __restrict__ bias,
    unsigned int* __restrict__ tbuf,     // [2 parity][256 b][512 col] tagged u32
    float* __restrict__ hlast)
{
    __shared__ __align__(16) unsigned short lds_B[16][ROWU];
    const int tid = threadIdx.x;
    const int bid = blockIdx.x;          // 64 WGs
    const int gi   = bid & 15;           // batch-group; members {gi,16+gi,32+gi,48+gi}
    const int mOwn = bid >> 4;           // own K-block (0..3), h-cols [mOwn*128,+128)

    const int w  = tid >> 6;             // wave 0..15
    const int l  = tid & 63;
    const int bb = l & 15;
    const int lg = l >> 4;
    const int jj = mOwn * 4 + (w >> 2);  // gate-slice (own 4 slices)
    const int mp = w & 3;
    const int m0 = 2 * mp, m1 = 2 * mp + 1;  // M-tiles within slice
    const int O4 = mOwn * 4;

    // ---- one-time: W -> 36 frags, pinned into AGPRs (144/lane, proven) ----
    short8 wA[NKT], wB[NKT];
#pragma unroll
    for (int kt = 0; kt < NKT; ++kt) {
        wA[kt] = *reinterpret_cast<const short8*>(
            wpack + (((size_t)(jj * 8 + m0) * NKT + kt) * 64 + l) * 8);
        wB[kt] = *reinterpret_cast<const short8*>(
            wpack + (((size_t)(jj * 8 + m1) * NKT + kt) * 64 + l) * 8);
    }
#pragma unroll
    for (int kt = 0; kt < NKT; ++kt) {
        asm volatile("" : "+a"(wA[kt]));
        asm volatile("" : "+a"(wB[kt]));
    }
    const int ghc0 = jj * 32 + 4 * m0 + lg;
    const int ghc1 = jj * 32 + 4 * m1 + lg;
    float bs0[4], bs1[4];
#pragma unroll
    for (int qg = 0; qg < 4; ++qg) {
        bs0[qg] = bias[qg * HSZ + ghc0];
        bs1[qg] = bias[qg * HSZ + ghc1];
    }
    float c0 = 0.f, c1 = 0.f;

    // prologue: zero h cols; stage x(0); prefetch x(1)
    {
        const int zb = tid >> 6, zc = (tid & 63) * 8;
        u32x4 z = {0u, 0u, 0u, 0u};
        *reinterpret_cast<u32x4*>(&lds_B[zb][zc]) = z;
    }
    const int sb = tid & 15, sc = (tid >> 4) & 31;   // x staging (tid<512)
    const float* xbase = input_seq + (size_t)(gi * BG + sb) * (TSTEPS * ISZ) + sc * 2;
    float2 xr = {0.f, 0.f};
    if (tid < 512) {
        xr = *reinterpret_cast<const float2*>(xbase);
        unsigned px = (unsigned)f2bf(xr.x) | ((unsigned)f2bf(xr.y) << 16);
        *reinterpret_cast<unsigned*>(&lds_B[sb][HSZ + sc * 2]) = px;
        xr = *reinterpret_cast<const float2*>(xbase + ISZ);   // x(1)
    }

    // poll mapping: thread (pb, c) covers, per peer block k, cols Bp*128+c*2,+1
    const int pb = tid >> 6, ch = tid & 63;
    const int B0 = (0 < mOwn) ? 0 : 1;
    const int B1 = (1 < mOwn) ? 1 : 2;
    const int B2 = (2 < mOwn) ? 2 : 3;
    const size_t prow = (size_t)(gi * BG + pb) * HSZ;        // u32 per row
    const u64t* pol0 = reinterpret_cast<const u64t*>(tbuf) + ((prow + B0 * 128) >> 1) + ch;
    const u64t* pol1 = reinterpret_cast<const u64t*>(tbuf) + ((prow + B1 * 128) >> 1) + ch;
    const u64t* pol2 = reinterpret_cast<const u64t*>(tbuf) + ((prow + B2 * 128) >> 1) + ch;
    const size_t PARU64 = PAR_STRIDE >> 1;
    // publish row base (u32)
    const size_t pubrow = (size_t)(gi * BG + bb) * HSZ;
    __syncthreads();

    for (int s = 0; s < TSTEPS; ++s) {
        f32x4 acc0 = {0.f, 0.f, 0.f, 0.f};
        f32x4 acc1 = {0.f, 0.f, 0.f, 0.f};
#define MF(KT, COL)                                                              \
        {                                                                        \
            const short8 bf = *reinterpret_cast<const short8*>(                  \
                &lds_B[bb][(COL) + lg * 8]);                                     \
            acc0 = __builtin_amdgcn_mfma_f32_16x16x32_bf16(wA[KT], bf, acc0, 0, 0, 0); \
            acc1 = __builtin_amdgcn_mfma_f32_16x16x32_bf16(wB[KT], bf, acc1, 0, 0, 0); \
        }
        // ---- part 1: own 4 kts + x 2 kts (no peer dependency) ----
        {
            const int ob = mOwn * 128;
            MF(0, ob) MF(1, ob + 32) MF(2, ob + 64) MF(3, ob + 96)
            MF(16, 512) MF(17, 544)
        }
        // ---- poll peer h(s): tagged u64s, 3 blocks, data = payload ----
        if (s > 0) {
            const size_t po = (size_t)(s & 1) * PARU64;
            const u64t want = ((u64t)(unsigned)s << 48) | ((u64t)(unsigned)s << 16);
            u64t v0, v1, v2;
            do {
                v0 = ld_tag64(pol0 + po);
                v1 = ld_tag64(pol1 + po);
                v2 = ld_tag64(pol2 + po);
            } while (((v0 & 0xFFFF0000FFFF0000ull) != want) ||
                     ((v1 & 0xFFFF0000FFFF0000ull) != want) ||
                     ((v2 & 0xFFFF0000FFFF0000ull) != want));
            const unsigned d0 = (unsigned)(v0 & 0xFFFFu) | ((unsigned)(v0 >> 16) & 0xFFFF0000u);
            const unsigned d1 = (unsigned)(v1 & 0xFFFFu) | ((unsigned)(v1 >> 16) & 0xFFFF0000u);
            const unsigned d2 = (unsigned)(v2 & 0xFFFFu) | ((unsigned)(v2 >> 16) & 0xFFFF0000u);
            *reinterpret_cast<unsigned*>(&lds_B[pb][B0 * 128 + ch * 2]) = d0;
            *reinterpret_cast<unsigned*>(&lds_B[pb][B1 * 128 + ch * 2]) = d1;
            *reinterpret_cast<unsigned*>(&lds_B[pb][B2 * 128 + ch * 2]) = d2;
        }
        __syncthreads();   // MID: peer staged; part-1 LDS reads done

        // ---- part 2: 12 peer kts (local 4..15) ----
#define MP(KT) MF(KT, (((KT) - 4) < O4 ? ((KT) - 4) : ((KT) - 4) + 4) * 32)
        MP(4) MP(5) MP(6) MP(7) MP(8) MP(9) MP(10) MP(11) MP(12) MP(13) MP(14) MP(15)
#undef MP
#undef MF

        // ---- cell update ----
        const float fg0 = sig_(acc0[0] + bs0[0]);
        const float ig0 = sig_(acc0[1] + bs0[1]);
        const float cp0 = tanh_(acc0[2] + bs0[2]);
        const float og0 = sig_(acc0[3] + bs0[3]);
        c0 = fg0 * c0 + ig0 * cp0;
        const float h0v = og0 * tanh_(c0);
        const float fg1 = sig_(acc1[0] + bs1[0]);
        const float ig1 = sig_(acc1[1] + bs1[1]);
        const float cp1 = tanh_(acc1[2] + bs1[2]);
        const float og1 = sig_(acc1[3] + bs1[3]);
        c1 = fg1 * c1 + ig1 * cp1;
        const float h1v = og1 * tanh_(c1);

        if (s == TSTEPS - 1) {
            hlast[(size_t)(gi * BG + bb) * HSZ + ghc0] = h0v;
            hlast[(size_t)(gi * BG + bb) * HSZ + ghc1] = h1v;
            break;
        }
        {
            const unsigned short hb0 = f2bf(h0v), hb1 = f2bf(h1v);
            lds_B[bb][ghc0] = hb0;               // own use (next part 1)
            lds_B[bb][ghc1] = hb1;
            const unsigned t16 = (unsigned)(s + 1) << 16;
            unsigned* pub = tbuf + (size_t)((s + 1) & 1) * PAR_STRIDE + pubrow;
            st_tag32(pub + ghc0, t16 | hb0);     // peer use (fires immediately)
            st_tag32(pub + ghc1, t16 | hb1);
        }
        // stage x(s+1); prefetch x(s+2)
        if (tid < 512) {
            unsigned px = (unsigned)f2bf(xr.x) | ((unsigned)f2bf(xr.y) << 16);
            *reinterpret_cast<unsigned*>(&lds_B[sb][HSZ + sc * 2]) = px;
            if (s + 2 < TSTEPS)
                xr = *reinterpret_cast<const float2*>(xbase + (size_t)(s + 2) * ISZ);
        }
        __syncthreads();   // END: own-h/x staged for next part 1
    }
}

// out[b] = h_last[b,:] . Wout + bout
__global__ void out_kernel(const float* __restrict__ hlast,
                           const float* __restrict__ wout,
                           const float* __restrict__ bout,
                           float* __restrict__ out)
{
    const int b = blockIdx.x;
    const int l = threadIdx.x;
    float p = 0.f;
    for (int k = l; k < HSZ; k += 64)
        p += hlast[(size_t)b * HSZ + k] * wout[k];
    for (int off = 32; off > 0; off >>= 1)
        p += __shfl_down(p, off, 64);
    if (l == 0) out[b] = p + bout[0];
}

extern "C" void kernel_launch(void* const* d_in, const int* in_sizes, int n_in,
                              void* d_out, int out_size, void* d_ws, size_t ws_size,
                              hipStream_t stream) {
    const float* input_seq = (const float*)d_in[0];
    const float* Kin       = (const float*)d_in[1];
    const float* R         = (const float*)d_in[2];
    const float* bias      = (const float*)d_in[3];
    const float* Wout      = (const float*)d_in[4];
    const float* bout      = (const float*)d_in[5];
    float* out = (float*)d_out;

    char* ws = (char*)d_ws;
    unsigned short* wpack = (unsigned short*)(ws);                    // 2,359,296 B
    unsigned int* tbuf    = (unsigned int*)(ws + 2359296);            // 2,097,152 B
    float* hlast          = (float*)(ws + 2359296 + 2097152);         //   524,288 B

    zero_tags<<<dim3(256), dim3(256), 0, stream>>>((u32x4*)tbuf);
    pack_w<<<dim3(576), dim3(256), 0, stream>>>(R, Kin, wpack);
    lstm_persist<<<dim3(64), dim3(1024), 0, stream>>>(
        wpack, input_seq, bias, tbuf, hlast);
    out_kernel<<<dim3(256), dim3(64), 0, stream>>>(hlast, Wout, bout, out);
}

// Round 10
// 2925.894 us; speedup vs baseline: 5.4703x; 2.2374x over previous
//
#include <hip/hip_runtime.h>

// LSTM: B=256, T=512, I=64, H=512, G=4H=2048.
// gates = W @ [h; x], W = [R | kernel^T], K = 576.
// Persistent kernel: 128 WGs x 512 threads = 16 batch-groups x 8 WGs.
// (Round-7 champion structure.) W pinned in AGPRs (144/lane), c in VGPRs.
// h exchange: TAGGED u32s ((s<<16)|bf16), relaxed agent-scope atomics,
// parity double-buffered; poll IS the data load.
// R10 changes vs R7: (1) publish fires straight from cell registers
// (scattered stores; lds_hn + barrier C deleted -> producer releases
// ~300-500 cyc earlier); (2) s_sleep(1) backoff in the poll loop.
#define TSTEPS 512
#define BATCH  256
#define ISZ    64
#define HSZ    512
#define GSZ    2048
#define NKT    18
#define BG     16
#define PAR_STRIDE 131072   // u32 per parity plane: 256*512

typedef __attribute__((ext_vector_type(8))) short short8;
typedef __attribute__((ext_vector_type(4))) float f32x4;
typedef __attribute__((ext_vector_type(4))) unsigned int u32x4;
typedef unsigned long long u64t;

static __device__ __forceinline__ unsigned short f2bf(float f) {
    unsigned int u = __float_as_uint(f);
    return (unsigned short)((u + 0x7fffu + ((u >> 16) & 1u)) >> 16);  // RNE
}
static __device__ __forceinline__ float sig_(float x) {
    return 1.0f / (1.0f + __expf(-x));
}
static __device__ __forceinline__ float tanh_(float x) {
    float e = __expf(-2.0f * fabsf(x));
    float t = (1.0f - e) / (1.0f + e);
    return copysignf(t, x);
}
static __device__ __forceinline__ u64t ld_tag64(const u64t* p) {
    return __hip_atomic_load(p, __ATOMIC_RELAXED, __HIP_MEMORY_SCOPE_AGENT);
}
static __device__ __forceinline__ void st_tag32(unsigned* p, unsigned v) {
    __hip_atomic_store(p, v, __ATOMIC_RELAXED, __HIP_MEMORY_SCOPE_AGENT);
}

// Pack W = [R | kernel^T] (fp32) into bf16 MFMA A-fragment order.
// Frag t = ((jj*8 + m)*18 + kt)*64 + lane; row r = 16m + (lane&15);
// gate q = r&3; hco = r>>2; global row = q*512 + jj*32 + hco.
__global__ void pack_w(const float* __restrict__ R, const float* __restrict__ Kin,
                       unsigned short* __restrict__ wpack)
{
    const int t  = blockIdx.x * 256 + threadIdx.x;
    const int l  = t & 63;
    const int kt = (t >> 6) % NKT;
    const int m  = (t / (64 * NKT)) & 7;
    const int jj = t / (64 * NKT * 8);
    const int r   = 16 * m + (l & 15);
    const int q   = r & 3;
    const int hco = r >> 2;
    const int grow  = q * HSZ + jj * 32 + hco;
    const int kbase = kt * 32 + (l >> 4) * 8;
    unsigned int pk[4];
#pragma unroll
    for (int p = 0; p < 4; ++p) {
        const int k0 = kbase + 2 * p;
        const int k1 = k0 + 1;
        const float f0 = (k0 < HSZ) ? R[(size_t)grow * HSZ + k0]
                                    : Kin[(size_t)(k0 - HSZ) * GSZ + grow];
        const float f1 = (k1 < HSZ) ? R[(size_t)grow * HSZ + k1]
                                    : Kin[(size_t)(k1 - HSZ) * GSZ + grow];
        pk[p] = (unsigned)f2bf(f0) | ((unsigned)f2bf(f1) << 16);
    }
    uint4 v = make_uint4(pk[0], pk[1], pk[2], pk[3]);
    *reinterpret_cast<uint4*>(wpack + (size_t)t * 8) = v;
}

// Zero tagged h buffer each launch (tag 0 matches no step >= 1): replay-safe.
__global__ void zero_tags(u32x4* __restrict__ hb) {
    u32x4 z = {0u, 0u, 0u, 0u};
    hb[blockIdx.x * 256 + threadIdx.x] = z;
}

__global__ __launch_bounds__(512, 1) void lstm_persist(
    const unsigned short* __restrict__ wpack,
    const float* __restrict__ input_seq,
    const float* __restrict__ bias,
    unsigned int* __restrict__ tbuf,     // [2 parity][256 b][512 col] tagged u32
    float* __restrict__ hlast)
{
    __shared__ __align__(16) unsigned short lds_B[16][584];   // [batch][k]
    const int tid = threadIdx.x;
    const int bid = blockIdx.x;
    const int gi = (bid & 7) + 8 * (bid >> 6);   // batch-group
    const int jw = (bid >> 3) & 7;               // h-col window [jw*64, +64)

    const int w  = tid >> 6;
    const int l  = tid & 63;
    const int bb = l & 15;
    const int lg = l >> 4;
    const int jj = 2 * jw + (w >> 2);
    const int mw = w & 3;
    const int m0 = 2 * mw, m1 = 2 * mw + 1;

    // ---- one-time: W fragments -> registers, PINNED into AGPRs ----
    short8 wA[NKT], wB[NKT];
#pragma unroll
    for (int kt = 0; kt < NKT; ++kt) {
        wA[kt] = *reinterpret_cast<const short8*>(
            wpack + (((size_t)(jj * 8 + m0) * NKT + kt) * 64 + l) * 8);
        wB[kt] = *reinterpret_cast<const short8*>(
            wpack + (((size_t)(jj * 8 + m1) * NKT + kt) * 64 + l) * 8);
    }
#pragma unroll
    for (int kt = 0; kt < NKT; ++kt) {
        asm volatile("" : "+a"(wA[kt]));   // pin: value lives in 4 AGPRs
        asm volatile("" : "+a"(wB[kt]));
    }
    const int hc0 = 4 * m0 + lg, hc1 = 4 * m1 + lg;
    const int gh0 = jj * 32 + hc0, gh1 = jj * 32 + hc1;
    float bs0[4], bs1[4];
#pragma unroll
    for (int qg = 0; qg < 4; ++qg) {
        bs0[qg] = bias[qg * HSZ + gh0];
        bs1[qg] = bias[qg * HSZ + gh1];
    }

    float c0 = 0.f, c1 = 0.f;

    // consumer mapping: thread (sb, sc) stages batch sb, cols [sc*16, +16)
    const int sb = tid & 15, sc = tid >> 4;
    const float* xbase = input_seq + (size_t)(gi * BG + sb) * (TSTEPS * ISZ) + sc * 2;
    float2 xr = *reinterpret_cast<const float2*>(xbase);

    const u64t* const hb0 = reinterpret_cast<const u64t*>(tbuf);
    const u64t* const hb1 = reinterpret_cast<const u64t*>(tbuf + (size_t)PAR_STRIDE);
    const size_t csrc = ((size_t)(gi * BG + sb) * HSZ + sc * 16) >> 1;  // u64 idx
    // publish row base (u32): this thread's batch row is bb
    const size_t pubrow = (size_t)(gi * BG + bb) * HSZ;

    for (int s = 0; s < TSTEPS; ++s) {
        // stage x(s) first (independent of the poll); prefetch x(s+1)
        {
            unsigned px = (unsigned)f2bf(xr.x) | ((unsigned)f2bf(xr.y) << 16);
            *reinterpret_cast<unsigned*>(&lds_B[sb][HSZ + sc * 2]) = px;
            if (s + 1 < TSTEPS)
                xr = *reinterpret_cast<const float2*>(xbase + (size_t)(s + 1) * ISZ);
        }
        // ---- acquire h(s): poll tagged data with s_sleep backoff ----
        if (s > 0) {
            const u64t* src = ((s & 1) ? hb1 : hb0) + csrc;
            const u64t want = ((u64t)(unsigned)s << 48) | ((u64t)(unsigned)s << 16);
            u64t v[8];
            bool ok;
            bool first = true;
            do {
                if (!first) __builtin_amdgcn_s_sleep(1);
                first = false;
                ok = true;
#pragma unroll
                for (int i = 0; i < 8; ++i)
                    v[i] = ld_tag64(src + i);
#pragma unroll
                for (int i = 0; i < 8; ++i)
                    ok = ok && ((v[i] & 0xFFFF0000FFFF0000ull) == want);
            } while (!ok);
            unsigned d[8];
#pragma unroll
            for (int i = 0; i < 8; ++i)
                d[i] = (unsigned)(v[i] & 0xFFFFu) |
                       ((unsigned)(v[i] >> 16) & 0xFFFF0000u);
            u32x4* dst = reinterpret_cast<u32x4*>(&lds_B[sb][sc * 16]);
            u32x4 lo = {d[0], d[1], d[2], d[3]};
            u32x4 hi = {d[4], d[5], d[6], d[7]};
            dst[0] = lo; dst[1] = hi;
        } else {
            u32x4 z = {0u, 0u, 0u, 0u};
            u32x4* dst = reinterpret_cast<u32x4*>(&lds_B[sb][sc * 16]);
            dst[0] = z; dst[1] = z;
        }
        __syncthreads();   // B: staging complete

        f32x4 acc0 = {0.f, 0.f, 0.f, 0.f};
        f32x4 acc1 = {0.f, 0.f, 0.f, 0.f};
#pragma unroll
        for (int kt = 0; kt < NKT; ++kt) {
            const short8 bf = *reinterpret_cast<const short8*>(
                &lds_B[bb][kt * 32 + lg * 8]);
            acc0 = __builtin_amdgcn_mfma_f32_16x16x32_bf16(wA[kt], bf, acc0, 0, 0, 0);
            acc1 = __builtin_amdgcn_mfma_f32_16x16x32_bf16(wB[kt], bf, acc1, 0, 0, 0);
        }

        // ---- lane-local cell update ----
        const float fg0 = sig_(acc0[0] + bs0[0]);
        const float ig0 = sig_(acc0[1] + bs0[1]);
        const float cp0 = tanh_(acc0[2] + bs0[2]);
        const float og0 = sig_(acc0[3] + bs0[3]);
        c0 = fg0 * c0 + ig0 * cp0;
        const float h0v = og0 * tanh_(c0);
        const float fg1 = sig_(acc1[0] + bs1[0]);
        const float ig1 = sig_(acc1[1] + bs1[1]);
        const float cp1 = tanh_(acc1[2] + bs1[2]);
        const float og1 = sig_(acc1[3] + bs1[3]);
        c1 = fg1 * c1 + ig1 * cp1;
        const float h1v = og1 * tanh_(c1);

        if (s == TSTEPS - 1) {
            hlast[(size_t)(gi * BG + bb) * HSZ + gh0] = h0v;
            hlast[(size_t)(gi * BG + bb) * HSZ + gh1] = h1v;
            break;
        }

        // ---- publish h(s+1) IMMEDIATELY from cell registers (scattered) ----
        {
            const unsigned t16 = (unsigned)(s + 1) << 16;
            unsigned* pub = tbuf + (size_t)((s + 1) & 1) * PAR_STRIDE + pubrow;
            st_tag32(pub + gh0, t16 | (unsigned)f2bf(h0v));
            st_tag32(pub + gh1, t16 | (unsigned)f2bf(h1v));
        }
        __syncthreads();   // E: all lds_B reads done before next staging
    }
}

// out[b] = h_last[b,:] . Wout + bout
__global__ void out_kernel(const float* __restrict__ hlast,
                           const float* __restrict__ wout,
                           const float* __restrict__ bout,
                           float* __restrict__ out)
{
    const int b = blockIdx.x;
    const int l = threadIdx.x;
    float p = 0.f;
    for (int k = l; k < HSZ; k += 64)
        p += hlast[(size_t)b * HSZ + k] * wout[k];
    for (int off = 32; off > 0; off >>= 1)
        p += __shfl_down(p, off, 64);
    if (l == 0) out[b] = p + bout[0];
}

extern "C" void kernel_launch(void* const* d_in, const int* in_sizes, int n_in,
                              void* d_out, int out_size, void* d_ws, size_t ws_size,
                              hipStream_t stream) {
    const float* input_seq = (const float*)d_in[0];
    const float* Kin       = (const float*)d_in[1];
    const float* R         = (const float*)d_in[2];
    const float* bias      = (const float*)d_in[3];
    const float* Wout      = (const float*)d_in[4];
    const float* bout      = (const float*)d_in[5];
    float* out = (float*)d_out;

    char* ws = (char*)d_ws;
    unsigned short* wpack = (unsigned short*)(ws);                    // 2,359,296 B
    unsigned int* tbuf    = (unsigned int*)(ws + 2359296);            // 1,048,576 B
    float* hlast          = (float*)(ws + 2359296 + 1048576);         //   524,288 B

    zero_tags<<<dim3(256), dim3(256), 0, stream>>>((u32x4*)tbuf);
    pack_w<<<dim3(576), dim3(256), 0, stream>>>(R, Kin, wpack);
    lstm_persist<<<dim3(128), dim3(512), 0, stream>>>(
        wpack, input_seq, bias, tbuf, hlast);
    out_kernel<<<dim3(256), dim3(64), 0, stream>>>(hlast, Wout, bout, out);
}

// Round 11
// 1347.181 us; speedup vs baseline: 11.8808x; 2.1719x over previous
//
#include <hip/hip_runtime.h>

// LSTM: B=256, T=512, I=64, H=512, G=4H=2048.
// gates = W @ [h; x], W = [R | kernel^T], K = 576.
// Persistent kernel: 128 WGs x 512 threads = 16 batch-groups x 8 WGs.
// (Round-7 champion.) W pinned in AGPRs (144/lane), c in VGPRs.
// h exchange: TAGGED u32s ((s<<16)|bf16), relaxed agent-scope atomics,
// parity double-buffered; poll IS the data load.
// R11 single change vs R7: COALESCED poll mapping (row=tid>>5, chunk=tid&31,
// loads strided 32 u64s) -> each load instr covers 256B contiguous per
// half-wave (~8x fewer fabric transactions; atomics are per-op at TCC).
#define TSTEPS 512
#define BATCH  256
#define ISZ    64
#define HSZ    512
#define GSZ    2048
#define NKT    18
#define BG     16
#define PAR_STRIDE 131072   // u32 per parity plane: 256*512

typedef __attribute__((ext_vector_type(8))) short short8;
typedef __attribute__((ext_vector_type(4))) float f32x4;
typedef __attribute__((ext_vector_type(4))) unsigned int u32x4;
typedef unsigned long long u64t;

static __device__ __forceinline__ unsigned short f2bf(float f) {
    unsigned int u = __float_as_uint(f);
    return (unsigned short)((u + 0x7fffu + ((u >> 16) & 1u)) >> 16);  // RNE
}
static __device__ __forceinline__ float sig_(float x) {
    return 1.0f / (1.0f + __expf(-x));
}
static __device__ __forceinline__ float tanh_(float x) {
    float e = __expf(-2.0f * fabsf(x));
    float t = (1.0f - e) / (1.0f + e);
    return copysignf(t, x);
}
static __device__ __forceinline__ u64t ld_tag64(const u64t* p) {
    return __hip_atomic_load(p, __ATOMIC_RELAXED, __HIP_MEMORY_SCOPE_AGENT);
}
static __device__ __forceinline__ void st_tag64(u64t* p, u64t v) {
    __hip_atomic_store(p, v, __ATOMIC_RELAXED, __HIP_MEMORY_SCOPE_AGENT);
}

// Pack W = [R | kernel^T] (fp32) into bf16 MFMA A-fragment order.
// Frag t = ((jj*8 + m)*18 + kt)*64 + lane; row r = 16m + (lane&15);
// gate q = r&3; hco = r>>2; global row = q*512 + jj*32 + hco.
__global__ void pack_w(const float* __restrict__ R, const float* __restrict__ Kin,
                       unsigned short* __restrict__ wpack)
{
    const int t  = blockIdx.x * 256 + threadIdx.x;
    const int l  = t & 63;
    const int kt = (t >> 6) % NKT;
    const int m  = (t / (64 * NKT)) & 7;
    const int jj = t / (64 * NKT * 8);
    const int r   = 16 * m + (l & 15);
    const int q   = r & 3;
    const int hco = r >> 2;
    const int grow  = q * HSZ + jj * 32 + hco;
    const int kbase = kt * 32 + (l >> 4) * 8;
    unsigned int pk[4];
#pragma unroll
    for (int p = 0; p < 4; ++p) {
        const int k0 = kbase + 2 * p;
        const int k1 = k0 + 1;
        const float f0 = (k0 < HSZ) ? R[(size_t)grow * HSZ + k0]
                                    : Kin[(size_t)(k0 - HSZ) * GSZ + grow];
        const float f1 = (k1 < HSZ) ? R[(size_t)grow * HSZ + k1]
                                    : Kin[(size_t)(k1 - HSZ) * GSZ + grow];
        pk[p] = (unsigned)f2bf(f0) | ((unsigned)f2bf(f1) << 16);
    }
    uint4 v = make_uint4(pk[0], pk[1], pk[2], pk[3]);
    *reinterpret_cast<uint4*>(wpack + (size_t)t * 8) = v;
}

// Zero tagged h buffer each launch (tag 0 matches no step >= 1): replay-safe.
__global__ void zero_tags(u32x4* __restrict__ hb) {
    u32x4 z = {0u, 0u, 0u, 0u};
    hb[blockIdx.x * 256 + threadIdx.x] = z;
}

__global__ __launch_bounds__(512, 1) void lstm_persist(
    const unsigned short* __restrict__ wpack,
    const float* __restrict__ input_seq,
    const float* __restrict__ bias,
    unsigned int* __restrict__ tbuf,     // [2 parity][256 b][512 col] tagged u32
    float* __restrict__ hlast)
{
    __shared__ __align__(16) unsigned short lds_B[16][584];   // [batch][k]
    __shared__ __align__(16) unsigned short lds_hn[16][68];   // new-h staging
    const int tid = threadIdx.x;
    const int bid = blockIdx.x;
    const int gi = (bid & 7) + 8 * (bid >> 6);   // batch-group
    const int jw = (bid >> 3) & 7;               // h-col window [jw*64, +64)

    const int w  = tid >> 6;
    const int l  = tid & 63;
    const int bb = l & 15;
    const int lg = l >> 4;
    const int jj = 2 * jw + (w >> 2);
    const int mw = w & 3;
    const int m0 = 2 * mw, m1 = 2 * mw + 1;

    // ---- one-time: W fragments -> registers, PINNED into AGPRs ----
    short8 wA[NKT], wB[NKT];
#pragma unroll
    for (int kt = 0; kt < NKT; ++kt) {
        wA[kt] = *reinterpret_cast<const short8*>(
            wpack + (((size_t)(jj * 8 + m0) * NKT + kt) * 64 + l) * 8);
        wB[kt] = *reinterpret_cast<const short8*>(
            wpack + (((size_t)(jj * 8 + m1) * NKT + kt) * 64 + l) * 8);
    }
#pragma unroll
    for (int kt = 0; kt < NKT; ++kt) {
        asm volatile("" : "+a"(wA[kt]));   // pin: value lives in 4 AGPRs
        asm volatile("" : "+a"(wB[kt]));
    }
    const int hc0 = 4 * m0 + lg, hc1 = 4 * m1 + lg;
    const int gh0 = jj * 32 + hc0, gh1 = jj * 32 + hc1;
    float bs0[4], bs1[4];
#pragma unroll
    for (int qg = 0; qg < 4; ++qg) {
        bs0[qg] = bias[qg * HSZ + gh0];
        bs1[qg] = bias[qg * HSZ + gh1];
    }

    float c0 = 0.f, c1 = 0.f;

    // x staging mapping (unchanged): thread (sb, sc)
    const int sb = tid & 15, sc = tid >> 4;
    const float* xbase = input_seq + (size_t)(gi * BG + sb) * (TSTEPS * ISZ) + sc * 2;
    float2 xr = *reinterpret_cast<const float2*>(xbase);

    const u64t* const hb0 = reinterpret_cast<const u64t*>(tbuf);
    const u64t* const hb1 = reinterpret_cast<const u64t*>(tbuf + (size_t)PAR_STRIDE);
    // COALESCED consumer mapping: row rr = tid>>5, chunk cch = tid&31.
    // Load i covers u64s [i*32, +32) of the row: 256B contiguous per half-wave.
    const int rr = tid >> 5, cch = tid & 31;
    const size_t csrc = (size_t)(gi * BG + rr) * 256 + cch;   // u64 idx
    // producer mapping (R7): thread (b_, pr) stores cols jw*64+pr*2 (+1)
    const int b_ = tid >> 5, pr = tid & 31;
    const size_t pdst = ((size_t)(gi * BG + b_) * HSZ + jw * 64 + pr * 2) >> 1;

    for (int s = 0; s < TSTEPS; ++s) {
        // stage x(s) first (independent of the poll); prefetch x(s+1)
        {
            unsigned px = (unsigned)f2bf(xr.x) | ((unsigned)f2bf(xr.y) << 16);
            *reinterpret_cast<unsigned*>(&lds_B[sb][HSZ + sc * 2]) = px;
            if (s + 1 < TSTEPS)
                xr = *reinterpret_cast<const float2*>(xbase + (size_t)(s + 1) * ISZ);
        }
        // ---- acquire h(s): poll tagged data (poll IS the load) ----
        if (s > 0) {
            const u64t* src = ((s & 1) ? hb1 : hb0) + csrc;
            const u64t want = ((u64t)(unsigned)s << 48) | ((u64t)(unsigned)s << 16);
            u64t v[8];
            bool ok;
            do {
                ok = true;
#pragma unroll
                for (int i = 0; i < 8; ++i)
                    v[i] = ld_tag64(src + (size_t)i * 32);
#pragma unroll
                for (int i = 0; i < 8; ++i)
                    ok = ok && ((v[i] & 0xFFFF0000FFFF0000ull) == want);
            } while (!ok);
#pragma unroll
            for (int i = 0; i < 8; ++i) {
                const unsigned d = (unsigned)(v[i] & 0xFFFFu) |
                                   ((unsigned)(v[i] >> 16) & 0xFFFF0000u);
                *reinterpret_cast<unsigned*>(&lds_B[rr][i * 64 + cch * 2]) = d;
            }
        } else {
#pragma unroll
            for (int i = 0; i < 8; ++i)
                *reinterpret_cast<unsigned*>(&lds_B[rr][i * 64 + cch * 2]) = 0u;
        }
        __syncthreads();   // B: staging complete

        f32x4 acc0 = {0.f, 0.f, 0.f, 0.f};
        f32x4 acc1 = {0.f, 0.f, 0.f, 0.f};
#pragma unroll
        for (int kt = 0; kt < NKT; ++kt) {
            const short8 bf = *reinterpret_cast<const short8*>(
                &lds_B[bb][kt * 32 + lg * 8]);
            acc0 = __builtin_amdgcn_mfma_f32_16x16x32_bf16(wA[kt], bf, acc0, 0, 0, 0);
            acc1 = __builtin_amdgcn_mfma_f32_16x16x32_bf16(wB[kt], bf, acc1, 0, 0, 0);
        }

        // ---- lane-local cell update ----
        const float fg0 = sig_(acc0[0] + bs0[0]);
        const float ig0 = sig_(acc0[1] + bs0[1]);
        const float cp0 = tanh_(acc0[2] + bs0[2]);
        const float og0 = sig_(acc0[3] + bs0[3]);
        c0 = fg0 * c0 + ig0 * cp0;
        const float h0v = og0 * tanh_(c0);
        const float fg1 = sig_(acc1[0] + bs1[0]);
        const float ig1 = sig_(acc1[1] + bs1[1]);
        const float cp1 = tanh_(acc1[2] + bs1[2]);
        const float og1 = sig_(acc1[3] + bs1[3]);
        c1 = fg1 * c1 + ig1 * cp1;
        const float h1v = og1 * tanh_(c1);

        if (s == TSTEPS - 1) {
            hlast[(size_t)(gi * BG + bb) * HSZ + gh0] = h0v;
            hlast[(size_t)(gi * BG + bb) * HSZ + gh1] = h1v;
            break;
        }
        // stage new h into LDS (WG col window [jw*64, +64))
        const int cw = (w >> 2) * 32;
        lds_hn[bb][cw + hc0] = f2bf(h0v);
        lds_hn[bb][cw + hc1] = f2bf(h1v);
        __syncthreads();   // C: lds_hn ready; lds_B MFMA reads done

        // ---- publish h(s+1): coalesced tagged u64 atomic stores ----
        {
            const unsigned h2 = *reinterpret_cast<const unsigned*>(&lds_hn[b_][pr * 2]);
            const unsigned t16 = (unsigned)(s + 1) << 16;
            const unsigned lo = (h2 & 0xFFFFu) | t16;
            const unsigned hi = (h2 >> 16) | t16;
            const u64t tagged = ((u64t)hi << 32) | (u64t)lo;
            u64t* dst = (u64t*)(tbuf + (size_t)((s + 1) & 1) * PAR_STRIDE) + pdst;
            st_tag64(dst, tagged);
        }
    }
}

// out[b] = h_last[b,:] . Wout + bout
__global__ void out_kernel(const float* __restrict__ hlast,
                           const float* __restrict__ wout,
                           const float* __restrict__ bout,
                           float* __restrict__ out)
{
    const int b = blockIdx.x;
    const int l = threadIdx.x;
    float p = 0.f;
    for (int k = l; k < HSZ; k += 64)
        p += hlast[(size_t)b * HSZ + k] * wout[k];
    for (int off = 32; off > 0; off >>= 1)
        p += __shfl_down(p, off, 64);
    if (l == 0) out[b] = p + bout[0];
}

extern "C" void kernel_launch(void* const* d_in, const int* in_sizes, int n_in,
                              void* d_out, int out_size, void* d_ws, size_t ws_size,
                              hipStream_t stream) {
    const float* input_seq = (const float*)d_in[0];
    const float* Kin       = (const float*)d_in[1];
    const float* R         = (const float*)d_in[2];
    const float* bias      = (const float*)d_in[3];
    const float* Wout      = (const float*)d_in[4];
    const float* bout      = (const float*)d_in[5];
    float* out = (float*)d_out;

    char* ws = (char*)d_ws;
    unsigned short* wpack = (unsigned short*)(ws);                    // 2,359,296 B
    unsigned int* tbuf    = (unsigned int*)(ws + 2359296);            // 1,048,576 B
    float* hlast          = (float*)(ws + 2359296 + 1048576);         //   524,288 B

    zero_tags<<<dim3(256), dim3(256), 0, stream>>>((u32x4*)tbuf);
    pack_w<<<dim3(576), dim3(256), 0, stream>>>(R, Kin, wpack);
    lstm_persist<<<dim3(128), dim3(512), 0, stream>>>(
        wpack, input_seq, bias, tbuf, hlast);
    out_kernel<<<dim3(256), dim3(64), 0, stream>>>(hlast, Wout, bout, out);
}